// Round 8
// baseline (152.845 us; speedup 1.0000x reference)
//
#include <hip/hip_runtime.h>
#include <hip/hip_bf16.h>

typedef __attribute__((ext_vector_type(4))) float f32x4;
typedef __attribute__((ext_vector_type(8))) short bf16x8;
typedef __attribute__((ext_vector_type(4))) short s16x4;
typedef __attribute__((ext_vector_type(4))) unsigned int u32x4;

#define DEV static __device__ __forceinline__

// fp32 -> bf16 round-to-nearest-even (finite values only)
DEV unsigned short f2b(float f) {
  union { float f; unsigned int u; } v; v.f = f;
  unsigned int u = v.u;
  return (unsigned short)((u + 0x7fffu + ((u >> 16) & 1u)) >> 16);
}

// async global->LDS, 16B per lane; lds base wave-uniform, lanes land at base + lane*16
DEV void gll16(const void* g, void* l) {
  __builtin_amdgcn_global_load_lds((__attribute__((address_space(1))) void*)g,
                                   (__attribute__((address_space(3))) void*)l,
                                   16, 0, 0);
}

// ---------------------------------------------------------------------------
// prep: fp32 -> bf16 conversion + weight repack (verified, unchanged).
// Blocks 0..8191: x conversion. 8192..8383: Wt tiles. 8384..8447: WoT tiles.
// ---------------------------------------------------------------------------
__global__ __launch_bounds__(256) void prep(const float* __restrict__ x,
                                            const float* __restrict__ Wq,
                                            const float* __restrict__ Wk,
                                            const float* __restrict__ Wv,
                                            const float* __restrict__ Wo,
                                            unsigned short* __restrict__ xb,
                                            unsigned short* __restrict__ Wt,
                                            unsigned short* __restrict__ WoT) {
  const int bid = blockIdx.x;
  if (bid < 8192) {                                    // x: 8388608 elems / 4
    int id = bid * 256 + threadIdx.x;
    f32x4 v = *(const f32x4*)(x + (long)id * 4);
    s16x4 o;
    o.x = (short)f2b(v.x); o.y = (short)f2b(v.y);
    o.z = (short)f2b(v.z); o.w = (short)f2b(v.w);
    *(s16x4*)(xb + (long)id * 4) = o;
    return;
  }

  __shared__ unsigned int L[64 * 65];
  const int tx = threadIdx.x & 63;
  const int ty = threadIdx.x >> 6;

  int tb = bid - 8192;
  if (tb < 192) {
    int proj = tb >> 6, h = (tb >> 3) & 7, c0 = (tb & 7) << 6;
    const float* W = (proj == 0) ? Wq : ((proj == 1) ? Wk : Wv);
    const float* base = W + (long)h * 32768 + (long)c0 * 64;  // [c][d]
#pragma unroll
    for (int i = 0; i < 16; i++) {
      int c = ty + i * 4;
      L[tx * 65 + c] = f2b(base[(long)c * 64 + tx]);    // L[d][c]
    }
    __syncthreads();
    unsigned short* out = Wt + ((long)(proj * 512 + h * 64)) * 512 + c0;
#pragma unroll
    for (int i = 0; i < 16; i++) {
      int d = ty + i * 4;
      out[(long)d * 512 + tx] = (unsigned short)L[d * 65 + tx];
    }
  } else {
    int t = tb - 192;
    int n0 = (t >> 3) << 6, c0 = (t & 7) << 6;
#pragma unroll
    for (int i = 0; i < 16; i++) {
      int c = ty + i * 4;
      L[tx * 65 + c] = f2b(Wo[(long)(c0 + c) * 512 + n0 + tx]);  // L[n][c]
    }
    __syncthreads();
    unsigned short* out = WoT + (long)n0 * 512 + c0;
#pragma unroll
    for (int i = 0; i < 16; i++) {
      int n = ty + i * 4;
      out[(long)n * 512 + tx] = (unsigned short)L[n * 65 + tx];
    }
  }
}

// ---------------------------------------------------------------------------
// Fused QKV-projection + causal attention. One block per (b,h), 512 threads
// (8 waves), 1 block/CU (119.8 KB LDS), grid 512 = 2 CU-rounds.
//
// P1 (round 11 rebuild): BK=32, 16 K-tiles, 3-buffer LDS ring (28 KB/buf,
// aliases the dead Q/K/V regions), SINGLE barrier + counted vmcnt per iter:
//   iter t: vmcnt(own)   [drains my tile-t issues, leaves t+1 in flight
//                         (~1.5 tiles ≈ 1000 cyc flight); NEVER a 0-age drain]
//           s_barrier    [RAW: all waves' t landed (their vmcnt preceded
//                         arrival); WAR: all reads of t-1 lgkm-retired before
//                         arrival, so staging after is safe]
//           stage(t+2)   [3-4 gll16 into buf (t+2)%3 == (t-1)%3]
//           setprio(1); 11 ds_read_b128 + 24 MFMA; setprio(0)
// own = 4 (waves 0-3: 2 A-segs + 2 B-segs) / 3 (waves 4-7: 2 A + 1 B).
// Swizzle: 4-cg family cg^((row>>1)&3) (round-4-verified, 2 lanes/bank).
// K-accumulation order identical to BK=64 version -> bit-identical acc.
//
// scatter/P2/P3 unchanged (verified round 7):
//   scatter: acc -> Q,K (cg^(row&7) swizzled), V transposed (Vt[d][j]).
//   P2: tile pair {u,7-u} per wave PAIR, chunks split by c32 parity.
//   P3: pair combine via f32 scratch aliased over dead Q/K; normalize; AO.
//
// LDS map (shorts): Qs[0,16384) Kl[16384,32768) Vt[32768,49664) Pl[49664,59904)
//   P1 ring aliases [0, 43008): buf k at k*14336 (A at +0, B at +8192).
// XCD swizzle: all 8 heads of a batch on one XCD (xb[b] fetched once).
// ---------------------------------------------------------------------------
__global__ __launch_bounds__(512, 2) void qkv_attn(const unsigned short* __restrict__ xb,
                                                   const unsigned short* __restrict__ Wt,
                                                   unsigned short* __restrict__ AO) {
  __shared__ unsigned short SM[59904];
  const int QS_OFF = 0, KL_OFF = 16384, VT_OFF = 32768, PL_OFF = 49664;

  const int tid = threadIdx.x;
  const int wave = tid >> 6, lane = tid & 63;
  const int quad = lane >> 4, l16 = lane & 15;

  // XCD-bijective swizzle (nwg = 512, q = 64, r = 0)
  const int xcd = blockIdx.x & 7, ci = blockIdx.x >> 3;
  const int wg = xcd * 64 + ci;
  const int b = wg >> 3, h = wg & 7;

  const unsigned short* Ag = xb + (long)b * 256 * 512;   // [256][512]

  // ---------------- P1: QKV GEMM (BK=32, ring-3, counted vmcnt) ----------
  const int wm = wave >> 2, wn = wave & 3;               // 2M x 4N
  const int row16 = lane >> 2;                           // row within 16-row seg
  const int scg = ((lane & 3) ^ ((lane >> 3) & 3)) * 8;  // pre-swizzled global cg

  f32x4 acc[8][3] = {};

  // stage tile t into ring buffer: A segs {2w,2w+1}; B segs {w} (+{8+w} w<4)
  auto stageP1 = [&](int t, int buf) {
    unsigned short* base = SM + buf * 14336;
#pragma unroll
    for (int i = 0; i < 2; i++) {
      int sa = wave * 2 + i;                             // 16 A segs x 16 rows
      gll16(Ag + (long)(sa * 16 + row16) * 512 + t * 32 + scg, base + sa * 512);
    }
    {
      int sb = wave;                                     // B segs 0..7
      int brow = sb * 16 + row16;
      int wrow = (sb >> 2) * 512 + h * 64 + (brow & 63);
      gll16(Wt + (long)wrow * 512 + t * 32 + scg, base + 8192 + sb * 512);
    }
    if (wave < 4) {
      int sb = 8 + wave;                                 // B segs 8..11
      int brow = sb * 16 + row16;
      int wrow = (sb >> 2) * 512 + h * 64 + (brow & 63);
      gll16(Wt + (long)wrow * 512 + t * 32 + scg, base + 8192 + sb * 512);
    }
  };

  const int rq32 = (quad ^ ((l16 >> 1) & 3)) * 8;        // un-swizzle for reader

  auto computeP1 = [&](int buf) {
    const unsigned short* base = SM + buf * 14336;
    bf16x8 af[8], bfv[3];
#pragma unroll
    for (int mt = 0; mt < 8; mt++)
      af[mt] = *(const bf16x8*)(base + (wm * 128 + mt * 16 + l16) * 32 + rq32);
#pragma unroll
    for (int nt = 0; nt < 3; nt++)
      bfv[nt] = *(const bf16x8*)(base + 8192 + (wn * 48 + nt * 16 + l16) * 32 + rq32);
#pragma unroll
    for (int mt = 0; mt < 8; mt++)
#pragma unroll
      for (int nt = 0; nt < 3; nt++)
        acc[mt][nt] = __builtin_amdgcn_mfma_f32_16x16x32_bf16(af[mt], bfv[nt], acc[mt][nt], 0, 0, 0);
  };

  stageP1(0, 0);
  stageP1(1, 1);

#pragma unroll
  for (int t = 0; t < 16; t++) {
    if (t < 15) {
      if (wave < 4) asm volatile("s_waitcnt vmcnt(4)" ::: "memory");
      else          asm volatile("s_waitcnt vmcnt(3)" ::: "memory");
    } else {
      asm volatile("s_waitcnt vmcnt(0)" ::: "memory");
    }
    __builtin_amdgcn_s_barrier();
    __builtin_amdgcn_sched_barrier(0);
    if (t < 14) stageP1(t + 2, (t + 2) % 3);
    __builtin_amdgcn_sched_barrier(0);
    __builtin_amdgcn_s_setprio(1);
    computeP1(t % 3);
    __builtin_amdgcn_s_setprio(0);
    __builtin_amdgcn_sched_barrier(0);
  }

  // ---------------- scatter acc -> Q/K/V LDS ----------------
  __syncthreads();   // all waves' P1 reads retired (scatter aliases the ring)
#pragma unroll
  for (int mt = 0; mt < 8; mt++) {
#pragma unroll
    for (int nt = 0; nt < 3; nt++) {
      const int g = wn * 48 + nt * 16;          // col base; +l16 per lane
      const int proj = g >> 6;                  // uniform over the 16-col tile
      const int j0 = wm * 128 + mt * 16 + quad * 4;
      if (proj == 2) {
        int dcol = (g & 63) + l16;
        unsigned int w0 = (unsigned)f2b(acc[mt][nt][0]) | ((unsigned)f2b(acc[mt][nt][1]) << 16);
        unsigned int w1 = (unsigned)f2b(acc[mt][nt][2]) | ((unsigned)f2b(acc[mt][nt][3]) << 16);
        unsigned int* vp = (unsigned int*)(SM + VT_OFF + dcol * 264 + j0);
        vp[0] = w0; vp[1] = w1;                 // Vt[dcol][j0..j0+3]
      } else {
        unsigned short* base = SM + (proj ? KL_OFF : QS_OFF);
        int d = (g & 63) + l16;
        int dhi = d >> 3, dlo = d & 7;
#pragma unroll
        for (int r2 = 0; r2 < 4; r2++) {
          int j = j0 + r2;
          base[j * 64 + ((dhi ^ (j & 7)) * 8) + dlo] = f2b(acc[mt][nt][r2]);
        }
      }
    }
  }
  __syncthreads();   // Q/K/V published to all waves

  // ---------------- P2: attention ----------------
  const int u = wave >> 1, par = wave & 1;     // pair u, parity split
  const int tiles2[2] = {u, 7 - u};

  bf16x8 qf[2][2][2];  // [ti][kc][mt]
#pragma unroll
  for (int ti = 0; ti < 2; ti++)
#pragma unroll
    for (int kc = 0; kc < 2; kc++)
#pragma unroll
      for (int mt = 0; mt < 2; mt++) {
        int row = tiles2[ti] * 32 + mt * 16 + l16;
        qf[ti][kc][mt] = *(const bf16x8*)(SM + QS_OFF + row * 64 +
                                          (((kc * 4 + quad) ^ (row & 7)) * 8));
      }

  f32x4 O[2][2][4] = {};      // [ti][mt][dt]
  float lsum[2][2][4] = {};   // [ti][mt][r]
  const float scale = 0.044194173824159216f;  // 1/sqrt(512)

#pragma unroll
  for (int ti = 0; ti < 2; ti++) {
    const int t = tiles2[ti];
    for (int c32 = par; c32 <= t; c32 += 2) {  // wave-uniform trip count
      f32x4 S[2][2] = {};
#pragma unroll
      for (int kc = 0; kc < 2; kc++) {
        bf16x8 kbf[2];
#pragma unroll
        for (int st = 0; st < 2; st++) {
          int jrow = c32 * 32 + st * 16 + l16;
          kbf[st] = *(const bf16x8*)(SM + KL_OFF + jrow * 64 +
                                     (((kc * 4 + quad) ^ (jrow & 7)) * 8));
        }
#pragma unroll
        for (int mt = 0; mt < 2; mt++)
#pragma unroll
          for (int st = 0; st < 2; st++)
            S[mt][st] = __builtin_amdgcn_mfma_f32_16x16x32_bf16(qf[ti][kc][mt], kbf[st], S[mt][st], 0, 0, 0);
      }
      const bool diag = (c32 == t);
#pragma unroll
      for (int mt = 0; mt < 2; mt++)
#pragma unroll
        for (int st = 0; st < 2; st++)
#pragma unroll
          for (int r = 0; r < 4; r++) {
            int trow = mt * 16 + quad * 4 + r;
            float p = __expf(S[mt][st][r] * scale);
            if (diag && (st * 16 + l16 > trow)) p = 0.0f;
            lsum[ti][mt][r] += p;
            SM[PL_OFF + wave * 1280 + trow * 40 + st * 16 + l16] = f2b(p);
          }
      bf16x8 pa[2], vbf[4];
#pragma unroll
      for (int mt = 0; mt < 2; mt++)
        pa[mt] = *(const bf16x8*)(SM + PL_OFF + wave * 1280 + (mt * 16 + l16) * 40 + quad * 8);
#pragma unroll
      for (int dt = 0; dt < 4; dt++)
        vbf[dt] = *(const bf16x8*)(SM + VT_OFF + (dt * 16 + l16) * 264 + c32 * 32 + quad * 8);
#pragma unroll
      for (int mt = 0; mt < 2; mt++)
#pragma unroll
        for (int dt = 0; dt < 4; dt++)
          O[ti][mt][dt] = __builtin_amdgcn_mfma_f32_16x16x32_bf16(pa[mt], vbf[dt], O[ti][mt][dt], 0, 0, 0);
    }
  }

  // ---------------- P3: pair combine + normalize + write ----------------
  float lred[2][2][4];
#pragma unroll
  for (int ti = 0; ti < 2; ti++)
#pragma unroll
    for (int mt = 0; mt < 2; mt++)
#pragma unroll
      for (int r = 0; r < 4; r++) {
        float s = lsum[ti][mt][r];
        s += __shfl_xor(s, 1); s += __shfl_xor(s, 2);
        s += __shfl_xor(s, 4); s += __shfl_xor(s, 8);
        lred[ti][mt][r] = s;
      }

  __syncthreads();   // all waves done reading Qs/Kl (scratch aliases them)

  float* Oscr = (float*)SM;                       // 4 pairs x 4096 f32 (64 KB)
  float* Lscr = (float*)(SM + PL_OFF);            // 4 pairs x 64 f32

  if (par == 1) {
#pragma unroll
    for (int ti = 0; ti < 2; ti++)
#pragma unroll
      for (int mt = 0; mt < 2; mt++)
#pragma unroll
        for (int dt = 0; dt < 4; dt++)
#pragma unroll
          for (int r = 0; r < 4; r++)
            Oscr[u * 4096 + (ti * 32 + mt * 16 + quad * 4 + r) * 64 + dt * 16 + l16] = O[ti][mt][dt][r];
    if (l16 == 0)
#pragma unroll
      for (int ti = 0; ti < 2; ti++)
#pragma unroll
        for (int mt = 0; mt < 2; mt++)
#pragma unroll
          for (int r = 0; r < 4; r++)
            Lscr[u * 64 + ti * 32 + mt * 16 + quad * 4 + r] = lred[ti][mt][r];
  }
  __syncthreads();

  if (par == 0) {
    float linv[2][2][4];
#pragma unroll
    for (int ti = 0; ti < 2; ti++)
#pragma unroll
      for (int mt = 0; mt < 2; mt++)
#pragma unroll
        for (int r = 0; r < 4; r++)
          linv[ti][mt][r] = 1.0f / (lred[ti][mt][r] +
                                    Lscr[u * 64 + ti * 32 + mt * 16 + quad * 4 + r]);
#pragma unroll
    for (int ti = 0; ti < 2; ti++)
#pragma unroll
      for (int mt = 0; mt < 2; mt++)
#pragma unroll
        for (int dt = 0; dt < 4; dt++)
#pragma unroll
          for (int r = 0; r < 4; r++) {
            float o = O[ti][mt][dt][r] +
                      Oscr[u * 4096 + (ti * 32 + mt * 16 + quad * 4 + r) * 64 + dt * 16 + l16];
            int t_ = tiles2[ti] * 32 + mt * 16 + quad * 4 + r;
            int d = dt * 16 + l16;
            AO[(long)(b * 256 + t_) * 512 + h * 64 + d] = f2b(o * linv[ti][mt][r]);
          }
  }
}

// ---------------------------------------------------------------------------
// C[M x N] = A[M x 512] * BT[N x 512]^T  — round-6 verified 2-phase kernel.
// Used only for the output projection (AO @ WoT -> out, N=512).
// ---------------------------------------------------------------------------
template <int F32OUT>
__global__ __launch_bounds__(256, 2) void gemm_bt(const unsigned short* __restrict__ A,
                                                  const unsigned short* __restrict__ BT,
                                                  void* __restrict__ Cv,
                                                  int N) {
  const int K = 512;
  __shared__ unsigned short As[2][128 * 64];
  __shared__ unsigned short Bs[2][128 * 64];

  const int tid = threadIdx.x;
  const int wave = tid >> 6, lane = tid & 63;
  const int quad = lane >> 4, l16 = lane & 15;
  const int wm = wave >> 1, wn = wave & 1;

  const int NB = N >> 7;
  const int nwg = gridDim.x;
  const int q = nwg >> 3, r = nwg & 7;
  const int xcd = blockIdx.x & 7, ci = blockIdx.x >> 3;
  const int wg = (xcd < r ? xcd * (q + 1) : r * (q + 1) + (xcd - r) * q) + ci;
  const int bn = wg % NB;
  const int bm = wg / NB;

  const int srow = lane >> 3;
  const int scol = ((lane & 7) ^ srow) * 8;

  f32x4 acc[4][4] = {};

  auto stage = [&](int kk, int buf) {
#pragma unroll
    for (int s = 0; s < 4; s++) {
      int seg = wave * 4 + s;
      int row = seg * 8 + srow;
      gll16(A + (long)(bm * 128 + row) * K + kk + scol, &As[buf][seg * 512]);
      gll16(BT + (long)(bn * 128 + row) * K + kk + scol, &Bs[buf][seg * 512]);
    }
  };

  auto compute = [&](int buf) {
#pragma unroll
    for (int kc = 0; kc < 2; kc++) {
      const int rq = (((kc * 4 + quad) ^ (l16 & 7)) * 8);
      bf16x8 af[4], bfv[4];
#pragma unroll
      for (int mt = 0; mt < 4; mt++)
        af[mt] = *(const bf16x8*)(&As[buf][(wm * 64 + mt * 16 + l16) * 64 + rq]);
#pragma unroll
      for (int nt = 0; nt < 4; nt++)
        bfv[nt] = *(const bf16x8*)(&Bs[buf][(wn * 64 + nt * 16 + l16) * 64 + rq]);
#pragma unroll
      for (int mt = 0; mt < 4; mt++)
#pragma unroll
        for (int nt = 0; nt < 4; nt++)
          acc[mt][nt] = __builtin_amdgcn_mfma_f32_16x16x32_bf16(af[mt], bfv[nt], acc[mt][nt], 0, 0, 0);
    }
  };

  stage(0, 0);
  asm volatile("s_waitcnt vmcnt(0)" ::: "memory");
  __builtin_amdgcn_s_barrier();
  __builtin_amdgcn_sched_barrier(0);

  int cur = 0;
#pragma unroll
  for (int t = 0; t < 8; t++) {
    if (t < 7) stage((t + 1) * 64, cur ^ 1);
    __builtin_amdgcn_sched_barrier(0);
    compute(cur);
    if (t < 7) {
      asm volatile("s_waitcnt vmcnt(0)" ::: "memory");
      __builtin_amdgcn_s_barrier();
      __builtin_amdgcn_sched_barrier(0);
      cur ^= 1;
    }
  }

#pragma unroll
  for (int mt = 0; mt < 4; mt++) {
#pragma unroll
    for (int nt = 0; nt < 4; nt++) {
      int row0 = bm * 128 + wm * 64 + mt * 16 + quad * 4;
      int col = bn * 128 + wn * 64 + nt * 16 + l16;
      if (F32OUT) {
        float* cp = (float*)Cv + (long)row0 * N + col;
#pragma unroll
        for (int r2 = 0; r2 < 4; r2++)
          cp[(long)r2 * N] = acc[mt][nt][r2];
      } else {
        unsigned short* cp = (unsigned short*)Cv + (long)row0 * N + col;
#pragma unroll
        for (int r2 = 0; r2 < 4; r2++)
          cp[(long)r2 * N] = f2b(acc[mt][nt][r2]);
      }
    }
  }
}

// ---------------------------------------------------------------------------
extern "C" void kernel_launch(void* const* d_in, const int* in_sizes, int n_in,
                              void* d_out, int out_size, void* d_ws, size_t ws_size,
                              hipStream_t stream) {
  const float* x  = (const float*)d_in[0];   // [16384][512] fp32
  const float* Wq = (const float*)d_in[1];   // [8][512][64] fp32
  const float* Wk = (const float*)d_in[2];
  const float* Wv = (const float*)d_in[3];
  const float* Wo = (const float*)d_in[4];   // [512][512] fp32

  unsigned short* Wt  = (unsigned short*)d_ws;                 // 1536*512
  unsigned short* WoT = Wt + 1536 * 512;                       // 512*512
  unsigned short* xb  = WoT + 512 * 512;                       // 16384*512
  unsigned short* AO  = xb + (long)16384 * 512;                // 16384*512
  float* out = (float*)d_out;                                  // [16384][512] fp32

  prep<<<8448, 256, 0, stream>>>(x, Wq, Wk, Wv, Wo, xb, Wt, WoT);

  qkv_attn<<<512, 512, 0, stream>>>(xb, Wt, AO);

  gemm_bt<1><<<512, 256, 0, stream>>>(AO, WoT, (void*)out, 512);
}

// Round 9
// 152.703 us; speedup vs baseline: 1.0009x; 1.0009x over previous
//
#include <hip/hip_runtime.h>
#include <hip/hip_bf16.h>

typedef __attribute__((ext_vector_type(4))) float f32x4;
typedef __attribute__((ext_vector_type(8))) short bf16x8;
typedef __attribute__((ext_vector_type(4))) short s16x4;
typedef __attribute__((ext_vector_type(4))) unsigned int u32x4;

#define DEV static __device__ __forceinline__

// fp32 -> bf16 round-to-nearest-even (finite values only)
DEV unsigned short f2b(float f) {
  union { float f; unsigned int u; } v; v.f = f;
  unsigned int u = v.u;
  return (unsigned short)((u + 0x7fffu + ((u >> 16) & 1u)) >> 16);
}

// async global->LDS, 16B per lane; lds base wave-uniform, lanes land at base + lane*16
DEV void gll16(const void* g, void* l) {
  __builtin_amdgcn_global_load_lds((__attribute__((address_space(1))) void*)g,
                                   (__attribute__((address_space(3))) void*)l,
                                   16, 0, 0);
}

// ---------------------------------------------------------------------------
// prep: fp32 -> bf16 conversion + weight repack (verified, unchanged).
// Blocks 0..8191: x conversion. 8192..8383: Wt tiles. 8384..8447: WoT tiles.
// ---------------------------------------------------------------------------
__global__ __launch_bounds__(256) void prep(const float* __restrict__ x,
                                            const float* __restrict__ Wq,
                                            const float* __restrict__ Wk,
                                            const float* __restrict__ Wv,
                                            const float* __restrict__ Wo,
                                            unsigned short* __restrict__ xb,
                                            unsigned short* __restrict__ Wt,
                                            unsigned short* __restrict__ WoT) {
  const int bid = blockIdx.x;
  if (bid < 8192) {                                    // x: 8388608 elems / 4
    int id = bid * 256 + threadIdx.x;
    f32x4 v = *(const f32x4*)(x + (long)id * 4);
    s16x4 o;
    o.x = (short)f2b(v.x); o.y = (short)f2b(v.y);
    o.z = (short)f2b(v.z); o.w = (short)f2b(v.w);
    *(s16x4*)(xb + (long)id * 4) = o;
    return;
  }

  __shared__ unsigned int L[64 * 65];
  const int tx = threadIdx.x & 63;
  const int ty = threadIdx.x >> 6;

  int tb = bid - 8192;
  if (tb < 192) {
    int proj = tb >> 6, h = (tb >> 3) & 7, c0 = (tb & 7) << 6;
    const float* W = (proj == 0) ? Wq : ((proj == 1) ? Wk : Wv);
    const float* base = W + (long)h * 32768 + (long)c0 * 64;  // [c][d]
#pragma unroll
    for (int i = 0; i < 16; i++) {
      int c = ty + i * 4;
      L[tx * 65 + c] = f2b(base[(long)c * 64 + tx]);    // L[d][c]
    }
    __syncthreads();
    unsigned short* out = Wt + ((long)(proj * 512 + h * 64)) * 512 + c0;
#pragma unroll
    for (int i = 0; i < 16; i++) {
      int d = ty + i * 4;
      out[(long)d * 512 + tx] = (unsigned short)L[d * 65 + tx];
    }
  } else {
    int t = tb - 192;
    int n0 = (t >> 3) << 6, c0 = (t & 7) << 6;
#pragma unroll
    for (int i = 0; i < 16; i++) {
      int c = ty + i * 4;
      L[tx * 65 + c] = f2b(Wo[(long)(c0 + c) * 512 + n0 + tx]);  // L[n][c]
    }
    __syncthreads();
    unsigned short* out = WoT + (long)n0 * 512 + c0;
#pragma unroll
    for (int i = 0; i < 16; i++) {
      int n = ty + i * 4;
      out[(long)n * 512 + tx] = (unsigned short)L[n * 65 + tx];
    }
  }
}

// ---------------------------------------------------------------------------
// Fused QKV-projection + causal attention. One block per (b,h), 512 threads
// (8 waves), 1 block/CU (~120 KB LDS), grid 512 = 2 CU-rounds.
//
// P1 (round 12): BK=32, 16 K-tiles, FOUR-buffer LDS ring (28 KB/buf, ring
// spans [0,57344) shorts, aliasing the dead Q/K/V/Pl regions), single
// barrier + counted vmcnt per iter:
//   iter t: vmcnt(2*own)  [drains my tile-t issues; leaves t+1,t+2 in flight
//                          (2 tiles ≈ 2 compute-windows of age); never 0-age]
//           s_barrier     [RAW: all waves' t landed; WAR: reads of t-1
//                          lgkm-retired in every wave before arrival]
//           stage(t+3)    [3-4 gll16 into buf (t+3)%4 == (t-1)%4]
//           setprio(1); 11 ds_read_b128 + 24 MFMA; setprio(0)
// own = 4 (waves 0-3) / 3 (waves 4-7). Tail: t=14 vmcnt(own), t=15 vmcnt(0).
// Swizzle: 4-cg family cg^((row>>1)&3) (verified). K-order identical ->
// bit-identical acc.
//
// Vt stride 264 -> 268 (byte stride 536 -> bank step 6: 16 distinct banks
// across l16 on vbf reads AND V-scatter writes, ~2-way vs 4-8-way; attacks
// the measured 1.1M SQ_LDS_BANK_CONFLICT).
// P2: setprio(1) around QK and PV MFMA clusters (m191 +4-7%).
//
// LDS map (shorts): Qs[0,16384) Kl[16384,32768) Vt[32768,49920) Pl[49920,60160)
// XCD swizzle: all 8 heads of a batch on one XCD (xb[b] fetched once).
// ---------------------------------------------------------------------------
__global__ __launch_bounds__(512, 2) void qkv_attn(const unsigned short* __restrict__ xb,
                                                   const unsigned short* __restrict__ Wt,
                                                   unsigned short* __restrict__ AO) {
  __shared__ unsigned short SM[60160];
  const int QS_OFF = 0, KL_OFF = 16384, VT_OFF = 32768, PL_OFF = 49920;
  const int VSTR = 268;

  const int tid = threadIdx.x;
  const int wave = tid >> 6, lane = tid & 63;
  const int quad = lane >> 4, l16 = lane & 15;

  // XCD-bijective swizzle (nwg = 512, q = 64, r = 0)
  const int xcd = blockIdx.x & 7, ci = blockIdx.x >> 3;
  const int wg = xcd * 64 + ci;
  const int b = wg >> 3, h = wg & 7;

  const unsigned short* Ag = xb + (long)b * 256 * 512;   // [256][512]

  // ---------------- P1: QKV GEMM (BK=32, ring-4, counted vmcnt) ----------
  const int wm = wave >> 2, wn = wave & 3;               // 2M x 4N
  const int row16 = lane >> 2;                           // row within 16-row seg
  const int scg = ((lane & 3) ^ ((lane >> 3) & 3)) * 8;  // pre-swizzled global cg

  f32x4 acc[8][3] = {};

  // stage tile t into ring buffer: A segs {2w,2w+1}; B segs {w} (+{8+w} w<4)
  auto stageP1 = [&](int t, int buf) {
    unsigned short* base = SM + buf * 14336;
#pragma unroll
    for (int i = 0; i < 2; i++) {
      int sa = wave * 2 + i;                             // 16 A segs x 16 rows
      gll16(Ag + (long)(sa * 16 + row16) * 512 + t * 32 + scg, base + sa * 512);
    }
    {
      int sb = wave;                                     // B segs 0..7
      int brow = sb * 16 + row16;
      int wrow = (sb >> 2) * 512 + h * 64 + (brow & 63);
      gll16(Wt + (long)wrow * 512 + t * 32 + scg, base + 8192 + sb * 512);
    }
    if (wave < 4) {
      int sb = 8 + wave;                                 // B segs 8..11
      int brow = sb * 16 + row16;
      int wrow = (sb >> 2) * 512 + h * 64 + (brow & 63);
      gll16(Wt + (long)wrow * 512 + t * 32 + scg, base + 8192 + sb * 512);
    }
  };

  const int rq32 = (quad ^ ((l16 >> 1) & 3)) * 8;        // un-swizzle for reader

  auto computeP1 = [&](int buf) {
    const unsigned short* base = SM + buf * 14336;
    bf16x8 af[8], bfv[3];
#pragma unroll
    for (int mt = 0; mt < 8; mt++)
      af[mt] = *(const bf16x8*)(base + (wm * 128 + mt * 16 + l16) * 32 + rq32);
#pragma unroll
    for (int nt = 0; nt < 3; nt++)
      bfv[nt] = *(const bf16x8*)(base + 8192 + (wn * 48 + nt * 16 + l16) * 32 + rq32);
#pragma unroll
    for (int mt = 0; mt < 8; mt++)
#pragma unroll
      for (int nt = 0; nt < 3; nt++)
        acc[mt][nt] = __builtin_amdgcn_mfma_f32_16x16x32_bf16(af[mt], bfv[nt], acc[mt][nt], 0, 0, 0);
  };

  stageP1(0, 0);
  stageP1(1, 1);
  stageP1(2, 2);

#pragma unroll
  for (int t = 0; t < 16; t++) {
    if (t <= 13) {
      if (wave < 4) asm volatile("s_waitcnt vmcnt(8)" ::: "memory");
      else          asm volatile("s_waitcnt vmcnt(6)" ::: "memory");
    } else if (t == 14) {
      if (wave < 4) asm volatile("s_waitcnt vmcnt(4)" ::: "memory");
      else          asm volatile("s_waitcnt vmcnt(3)" ::: "memory");
    } else {
      asm volatile("s_waitcnt vmcnt(0)" ::: "memory");
    }
    __builtin_amdgcn_s_barrier();
    __builtin_amdgcn_sched_barrier(0);
    if (t < 13) stageP1(t + 3, (t + 3) & 3);
    __builtin_amdgcn_sched_barrier(0);
    __builtin_amdgcn_s_setprio(1);
    computeP1(t & 3);
    __builtin_amdgcn_s_setprio(0);
    __builtin_amdgcn_sched_barrier(0);
  }

  // ---------------- scatter acc -> Q/K/V LDS ----------------
  __syncthreads();   // all waves' P1 reads retired (scatter aliases the ring)
#pragma unroll
  for (int mt = 0; mt < 8; mt++) {
#pragma unroll
    for (int nt = 0; nt < 3; nt++) {
      const int g = wn * 48 + nt * 16;          // col base; +l16 per lane
      const int proj = g >> 6;                  // uniform over the 16-col tile
      const int j0 = wm * 128 + mt * 16 + quad * 4;
      if (proj == 2) {
        int dcol = (g & 63) + l16;
        unsigned int w0 = (unsigned)f2b(acc[mt][nt][0]) | ((unsigned)f2b(acc[mt][nt][1]) << 16);
        unsigned int w1 = (unsigned)f2b(acc[mt][nt][2]) | ((unsigned)f2b(acc[mt][nt][3]) << 16);
        unsigned int* vp = (unsigned int*)(SM + VT_OFF + dcol * VSTR + j0);
        vp[0] = w0; vp[1] = w1;                 // Vt[dcol][j0..j0+3]
      } else {
        unsigned short* base = SM + (proj ? KL_OFF : QS_OFF);
        int d = (g & 63) + l16;
        int dhi = d >> 3, dlo = d & 7;
#pragma unroll
        for (int r2 = 0; r2 < 4; r2++) {
          int j = j0 + r2;
          base[j * 64 + ((dhi ^ (j & 7)) * 8) + dlo] = f2b(acc[mt][nt][r2]);
        }
      }
    }
  }
  __syncthreads();   // Q/K/V published to all waves

  // ---------------- P2: attention ----------------
  const int u = wave >> 1, par = wave & 1;     // pair u, parity split
  const int tiles2[2] = {u, 7 - u};

  bf16x8 qf[2][2][2];  // [ti][kc][mt]
#pragma unroll
  for (int ti = 0; ti < 2; ti++)
#pragma unroll
    for (int kc = 0; kc < 2; kc++)
#pragma unroll
      for (int mt = 0; mt < 2; mt++) {
        int row = tiles2[ti] * 32 + mt * 16 + l16;
        qf[ti][kc][mt] = *(const bf16x8*)(SM + QS_OFF + row * 64 +
                                          (((kc * 4 + quad) ^ (row & 7)) * 8));
      }

  f32x4 O[2][2][4] = {};      // [ti][mt][dt]
  float lsum[2][2][4] = {};   // [ti][mt][r]
  const float scale = 0.044194173824159216f;  // 1/sqrt(512)

#pragma unroll
  for (int ti = 0; ti < 2; ti++) {
    const int t = tiles2[ti];
    for (int c32 = par; c32 <= t; c32 += 2) {  // wave-uniform trip count
      f32x4 S[2][2] = {};
      __builtin_amdgcn_s_setprio(1);
#pragma unroll
      for (int kc = 0; kc < 2; kc++) {
        bf16x8 kbf[2];
#pragma unroll
        for (int st = 0; st < 2; st++) {
          int jrow = c32 * 32 + st * 16 + l16;
          kbf[st] = *(const bf16x8*)(SM + KL_OFF + jrow * 64 +
                                     (((kc * 4 + quad) ^ (jrow & 7)) * 8));
        }
#pragma unroll
        for (int mt = 0; mt < 2; mt++)
#pragma unroll
          for (int st = 0; st < 2; st++)
            S[mt][st] = __builtin_amdgcn_mfma_f32_16x16x32_bf16(qf[ti][kc][mt], kbf[st], S[mt][st], 0, 0, 0);
      }
      __builtin_amdgcn_s_setprio(0);
      const bool diag = (c32 == t);
#pragma unroll
      for (int mt = 0; mt < 2; mt++)
#pragma unroll
        for (int st = 0; st < 2; st++)
#pragma unroll
          for (int r = 0; r < 4; r++) {
            int trow = mt * 16 + quad * 4 + r;
            float p = __expf(S[mt][st][r] * scale);
            if (diag && (st * 16 + l16 > trow)) p = 0.0f;
            lsum[ti][mt][r] += p;
            SM[PL_OFF + wave * 1280 + trow * 40 + st * 16 + l16] = f2b(p);
          }
      bf16x8 pa[2], vbf[4];
#pragma unroll
      for (int mt = 0; mt < 2; mt++)
        pa[mt] = *(const bf16x8*)(SM + PL_OFF + wave * 1280 + (mt * 16 + l16) * 40 + quad * 8);
#pragma unroll
      for (int dt = 0; dt < 4; dt++)
        vbf[dt] = *(const bf16x8*)(SM + VT_OFF + (dt * 16 + l16) * VSTR + c32 * 32 + quad * 8);
      __builtin_amdgcn_s_setprio(1);
#pragma unroll
      for (int mt = 0; mt < 2; mt++)
#pragma unroll
        for (int dt = 0; dt < 4; dt++)
          O[ti][mt][dt] = __builtin_amdgcn_mfma_f32_16x16x32_bf16(pa[mt], vbf[dt], O[ti][mt][dt], 0, 0, 0);
      __builtin_amdgcn_s_setprio(0);
    }
  }

  // ---------------- P3: pair combine + normalize + write ----------------
  float lred[2][2][4];
#pragma unroll
  for (int ti = 0; ti < 2; ti++)
#pragma unroll
    for (int mt = 0; mt < 2; mt++)
#pragma unroll
      for (int r = 0; r < 4; r++) {
        float s = lsum[ti][mt][r];
        s += __shfl_xor(s, 1); s += __shfl_xor(s, 2);
        s += __shfl_xor(s, 4); s += __shfl_xor(s, 8);
        lred[ti][mt][r] = s;
      }

  __syncthreads();   // all waves done reading Qs/Kl (scratch aliases them)

  float* Oscr = (float*)SM;                       // 4 pairs x 4096 f32 (64 KB)
  float* Lscr = (float*)(SM + PL_OFF);            // 4 pairs x 64 f32

  if (par == 1) {
#pragma unroll
    for (int ti = 0; ti < 2; ti++)
#pragma unroll
      for (int mt = 0; mt < 2; mt++)
#pragma unroll
        for (int dt = 0; dt < 4; dt++)
#pragma unroll
          for (int r = 0; r < 4; r++)
            Oscr[u * 4096 + (ti * 32 + mt * 16 + quad * 4 + r) * 64 + dt * 16 + l16] = O[ti][mt][dt][r];
    if (l16 == 0)
#pragma unroll
      for (int ti = 0; ti < 2; ti++)
#pragma unroll
        for (int mt = 0; mt < 2; mt++)
#pragma unroll
          for (int r = 0; r < 4; r++)
            Lscr[u * 64 + ti * 32 + mt * 16 + quad * 4 + r] = lred[ti][mt][r];
  }
  __syncthreads();

  if (par == 0) {
    float linv[2][2][4];
#pragma unroll
    for (int ti = 0; ti < 2; ti++)
#pragma unroll
      for (int mt = 0; mt < 2; mt++)
#pragma unroll
        for (int r = 0; r < 4; r++)
          linv[ti][mt][r] = 1.0f / (lred[ti][mt][r] +
                                    Lscr[u * 64 + ti * 32 + mt * 16 + quad * 4 + r]);
#pragma unroll
    for (int ti = 0; ti < 2; ti++)
#pragma unroll
      for (int mt = 0; mt < 2; mt++)
#pragma unroll
        for (int dt = 0; dt < 4; dt++)
#pragma unroll
          for (int r = 0; r < 4; r++) {
            float o = O[ti][mt][dt][r] +
                      Oscr[u * 4096 + (ti * 32 + mt * 16 + quad * 4 + r) * 64 + dt * 16 + l16];
            int t_ = tiles2[ti] * 32 + mt * 16 + quad * 4 + r;
            int d = dt * 16 + l16;
            AO[(long)(b * 256 + t_) * 512 + h * 64 + d] = f2b(o * linv[ti][mt][r]);
          }
  }
}

// ---------------------------------------------------------------------------
// C[M x N] = A[M x 512] * BT[N x 512]^T  — round-6 verified 2-phase kernel.
// Used only for the output projection (AO @ WoT -> out, N=512).
// ---------------------------------------------------------------------------
template <int F32OUT>
__global__ __launch_bounds__(256, 2) void gemm_bt(const unsigned short* __restrict__ A,
                                                  const unsigned short* __restrict__ BT,
                                                  void* __restrict__ Cv,
                                                  int N) {
  const int K = 512;
  __shared__ unsigned short As[2][128 * 64];
  __shared__ unsigned short Bs[2][128 * 64];

  const int tid = threadIdx.x;
  const int wave = tid >> 6, lane = tid & 63;
  const int quad = lane >> 4, l16 = lane & 15;
  const int wm = wave >> 1, wn = wave & 1;

  const int NB = N >> 7;
  const int nwg = gridDim.x;
  const int q = nwg >> 3, r = nwg & 7;
  const int xcd = blockIdx.x & 7, ci = blockIdx.x >> 3;
  const int wg = (xcd < r ? xcd * (q + 1) : r * (q + 1) + (xcd - r) * q) + ci;
  const int bn = wg % NB;
  const int bm = wg / NB;

  const int srow = lane >> 3;
  const int scol = ((lane & 7) ^ srow) * 8;

  f32x4 acc[4][4] = {};

  auto stage = [&](int kk, int buf) {
#pragma unroll
    for (int s = 0; s < 4; s++) {
      int seg = wave * 4 + s;
      int row = seg * 8 + srow;
      gll16(A + (long)(bm * 128 + row) * K + kk + scol, &As[buf][seg * 512]);
      gll16(BT + (long)(bn * 128 + row) * K + kk + scol, &Bs[buf][seg * 512]);
    }
  };

  auto compute = [&](int buf) {
#pragma unroll
    for (int kc = 0; kc < 2; kc++) {
      const int rq = (((kc * 4 + quad) ^ (l16 & 7)) * 8);
      bf16x8 af[4], bfv[4];
#pragma unroll
      for (int mt = 0; mt < 4; mt++)
        af[mt] = *(const bf16x8*)(&As[buf][(wm * 64 + mt * 16 + l16) * 64 + rq]);
#pragma unroll
      for (int nt = 0; nt < 4; nt++)
        bfv[nt] = *(const bf16x8*)(&Bs[buf][(wn * 64 + nt * 16 + l16) * 64 + rq]);
#pragma unroll
      for (int mt = 0; mt < 4; mt++)
#pragma unroll
        for (int nt = 0; nt < 4; nt++)
          acc[mt][nt] = __builtin_amdgcn_mfma_f32_16x16x32_bf16(af[mt], bfv[nt], acc[mt][nt], 0, 0, 0);
    }
  };

  stage(0, 0);
  asm volatile("s_waitcnt vmcnt(0)" ::: "memory");
  __builtin_amdgcn_s_barrier();
  __builtin_amdgcn_sched_barrier(0);

  int cur = 0;
#pragma unroll
  for (int t = 0; t < 8; t++) {
    if (t < 7) stage((t + 1) * 64, cur ^ 1);
    __builtin_amdgcn_sched_barrier(0);
    compute(cur);
    if (t < 7) {
      asm volatile("s_waitcnt vmcnt(0)" ::: "memory");
      __builtin_amdgcn_s_barrier();
      __builtin_amdgcn_sched_barrier(0);
      cur ^= 1;
    }
  }

#pragma unroll
  for (int mt = 0; mt < 4; mt++) {
#pragma unroll
    for (int nt = 0; nt < 4; nt++) {
      int row0 = bm * 128 + wm * 64 + mt * 16 + quad * 4;
      int col = bn * 128 + wn * 64 + nt * 16 + l16;
      if (F32OUT) {
        float* cp = (float*)Cv + (long)row0 * N + col;
#pragma unroll
        for (int r2 = 0; r2 < 4; r2++)
          cp[(long)r2 * N] = acc[mt][nt][r2];
      } else {
        unsigned short* cp = (unsigned short*)Cv + (long)row0 * N + col;
#pragma unroll
        for (int r2 = 0; r2 < 4; r2++)
          cp[(long)r2 * N] = f2b(acc[mt][nt][r2]);
      }
    }
  }
}

// ---------------------------------------------------------------------------
extern "C" void kernel_launch(void* const* d_in, const int* in_sizes, int n_in,
                              void* d_out, int out_size, void* d_ws, size_t ws_size,
                              hipStream_t stream) {
  const float* x  = (const float*)d_in[0];   // [16384][512] fp32
  const float* Wq = (const float*)d_in[1];   // [8][512][64] fp32
  const float* Wk = (const float*)d_in[2];
  const float* Wv = (const float*)d_in[3];
  const float* Wo = (const float*)d_in[4];   // [512][512] fp32

  unsigned short* Wt  = (unsigned short*)d_ws;                 // 1536*512
  unsigned short* WoT = Wt + 1536 * 512;                       // 512*512
  unsigned short* xb  = WoT + 512 * 512;                       // 16384*512
  unsigned short* AO  = xb + (long)16384 * 512;                // 16384*512
  float* out = (float*)d_out;                                  // [16384][512] fp32

  prep<<<8448, 256, 0, stream>>>(x, Wq, Wk, Wv, Wo, xb, Wt, WoT);

  qkv_attn<<<512, 512, 0, stream>>>(xb, Wt, AO);

  gemm_bt<1><<<512, 256, 0, stream>>>(AO, WoT, (void*)out, 512);
}

// Round 10
// 149.882 us; speedup vs baseline: 1.0198x; 1.0188x over previous
//
#include <hip/hip_runtime.h>
#include <hip/hip_bf16.h>

typedef __attribute__((ext_vector_type(4))) float f32x4;
typedef __attribute__((ext_vector_type(8))) short bf16x8;
typedef __attribute__((ext_vector_type(4))) short s16x4;
typedef __attribute__((ext_vector_type(4))) unsigned int u32x4;

#define DEV static __device__ __forceinline__

// fp32 -> bf16 round-to-nearest-even (finite values only)
DEV unsigned short f2b(float f) {
  union { float f; unsigned int u; } v; v.f = f;
  unsigned int u = v.u;
  return (unsigned short)((u + 0x7fffu + ((u >> 16) & 1u)) >> 16);
}

// async global->LDS, 16B per lane; lds base wave-uniform, lanes land at base + lane*16
DEV void gll16(const void* g, void* l) {
  __builtin_amdgcn_global_load_lds((__attribute__((address_space(1))) void*)g,
                                   (__attribute__((address_space(3))) void*)l,
                                   16, 0, 0);
}

// ---------------------------------------------------------------------------
// prep: fp32 -> bf16 conversion + weight repack (verified, unchanged).
// Blocks 0..8191: x conversion. 8192..8383: Wt tiles. 8384..8447: WoT tiles.
// ---------------------------------------------------------------------------
__global__ __launch_bounds__(256) void prep(const float* __restrict__ x,
                                            const float* __restrict__ Wq,
                                            const float* __restrict__ Wk,
                                            const float* __restrict__ Wv,
                                            const float* __restrict__ Wo,
                                            unsigned short* __restrict__ xb,
                                            unsigned short* __restrict__ Wt,
                                            unsigned short* __restrict__ WoT) {
  const int bid = blockIdx.x;
  if (bid < 8192) {                                    // x: 8388608 elems / 4
    int id = bid * 256 + threadIdx.x;
    f32x4 v = *(const f32x4*)(x + (long)id * 4);
    s16x4 o;
    o.x = (short)f2b(v.x); o.y = (short)f2b(v.y);
    o.z = (short)f2b(v.z); o.w = (short)f2b(v.w);
    *(s16x4*)(xb + (long)id * 4) = o;
    return;
  }

  __shared__ unsigned int L[64 * 65];
  const int tx = threadIdx.x & 63;
  const int ty = threadIdx.x >> 6;

  int tb = bid - 8192;
  if (tb < 192) {
    int proj = tb >> 6, h = (tb >> 3) & 7, c0 = (tb & 7) << 6;
    const float* W = (proj == 0) ? Wq : ((proj == 1) ? Wk : Wv);
    const float* base = W + (long)h * 32768 + (long)c0 * 64;  // [c][d]
#pragma unroll
    for (int i = 0; i < 16; i++) {
      int c = ty + i * 4;
      L[tx * 65 + c] = f2b(base[(long)c * 64 + tx]);    // L[d][c]
    }
    __syncthreads();
    unsigned short* out = Wt + ((long)(proj * 512 + h * 64)) * 512 + c0;
#pragma unroll
    for (int i = 0; i < 16; i++) {
      int d = ty + i * 4;
      out[(long)d * 512 + tx] = (unsigned short)L[d * 65 + tx];
    }
  } else {
    int t = tb - 192;
    int n0 = (t >> 3) << 6, c0 = (t & 7) << 6;
#pragma unroll
    for (int i = 0; i < 16; i++) {
      int c = ty + i * 4;
      L[tx * 65 + c] = f2b(Wo[(long)(c0 + c) * 512 + n0 + tx]);  // L[n][c]
    }
    __syncthreads();
    unsigned short* out = WoT + (long)n0 * 512 + c0;
#pragma unroll
    for (int i = 0; i < 16; i++) {
      int n = ty + i * 4;
      out[(long)n * 512 + tx] = (unsigned short)L[n * 65 + tx];
    }
  }
}

// ---------------------------------------------------------------------------
// Fused QKV-projection + causal attention. One block per (b,h), 512 threads
// (8 waves), 1 block/CU (~120 KB LDS), grid 512 = 2 CU-rounds.
//
// ROUND 13 = round-7 exact structure (the 148.2 best) + two validated deltas:
//   (a) Vt stride 264 -> 268 (bank step 6: SQ_LDS_BANK_CONFLICT 1.10M->672K,
//       measured round 9, no downside);
//   (b) setprio(1) around P2's QK and PV MFMA clusters (m191 +4-7% attn).
//
// P1: QKV = xb[b] @ Wt_h^T (256 x 192, K=512, BK=64), 2-phase dbuf, verified
//     gll16 staging (cg^(row&7) swizzle). Waves 2M x 4N, acc[8][3].
// scatter: acc -> Q,K (cg^(row&7) swizzled [256][64]), V transposed Vt[d][j].
// P2: tile pair {u,7-u} per wave PAIR, chunks split by c32 parity.
// P3: pair combine via f32 scratch aliased over dead Q/K; normalize; AO.
//
// LDS map (shorts): Qs[0,16384) Kl[16384,32768) Vt[32768,49920) Pl[49920,60160)
//   P1 aliases: As{0,16384} x2, Bs{32768,45056} x2 (dead before scatter;
//   Bs[1] tops at 57344 < 60160, overlapping only P1-dead Pl).
// XCD swizzle: all 8 heads of a batch on one XCD (xb[b] fetched once).
// ---------------------------------------------------------------------------
__global__ __launch_bounds__(512, 2) void qkv_attn(const unsigned short* __restrict__ xb,
                                                   const unsigned short* __restrict__ Wt,
                                                   unsigned short* __restrict__ AO) {
  __shared__ unsigned short SM[60160];
  const int QS_OFF = 0, KL_OFF = 16384, VT_OFF = 32768, PL_OFF = 49920;
  const int VSTR = 268;
  const int ASO[2] = {0, 16384};
  const int BSO[2] = {32768, 45056};

  const int tid = threadIdx.x;
  const int wave = tid >> 6, lane = tid & 63;
  const int quad = lane >> 4, l16 = lane & 15;

  // XCD-bijective swizzle (nwg = 512, q = 64, r = 0)
  const int xcd = blockIdx.x & 7, ci = blockIdx.x >> 3;
  const int wg = xcd * 64 + ci;
  const int b = wg >> 3, h = wg & 7;

  const unsigned short* Ag = xb + (long)b * 256 * 512;   // [256][512]

  // ---------------- P1: QKV GEMM (BK=64, 2-phase dbuf — round-7 exact) ----
  const int wm = wave >> 2, wn = wave & 3;               // 2M x 4N
  const int srow = lane >> 3;                            // row within 8-row seg
  const int scol = ((lane & 7) ^ srow) * 8;              // pre-swizzled global col

  f32x4 acc[8][3] = {};

  auto stage = [&](int kk, int buf) {
#pragma unroll
    for (int s = 0; s < 4; s++) {                        // A: 32 segs x 8 rows
      int seg = wave * 4 + s;
      int row = seg * 8 + srow;
      gll16(Ag + (long)row * 512 + kk + scol, SM + ASO[buf] + seg * 512);
    }
#pragma unroll
    for (int s = 0; s < 3; s++) {                        // B: 24 segs x 8 rows
      int seg = wave * 3 + s;
      int proj = seg >> 3;
      int wrow = proj * 512 + h * 64 + (seg & 7) * 8 + srow;
      gll16(Wt + (long)wrow * 512 + kk + scol, SM + BSO[buf] + seg * 512);
    }
  };

  auto compute = [&](int buf) {
#pragma unroll
    for (int kc = 0; kc < 2; kc++) {
      const int rq = (((kc * 4 + quad) ^ (l16 & 7)) * 8);
      bf16x8 af[8], bfv[3];
#pragma unroll
      for (int mt = 0; mt < 8; mt++)
        af[mt] = *(const bf16x8*)(SM + ASO[buf] + (wm * 128 + mt * 16 + l16) * 64 + rq);
#pragma unroll
      for (int nt = 0; nt < 3; nt++)
        bfv[nt] = *(const bf16x8*)(SM + BSO[buf] + (wn * 48 + nt * 16 + l16) * 64 + rq);
#pragma unroll
      for (int mt = 0; mt < 8; mt++)
#pragma unroll
        for (int nt = 0; nt < 3; nt++)
          acc[mt][nt] = __builtin_amdgcn_mfma_f32_16x16x32_bf16(af[mt], bfv[nt], acc[mt][nt], 0, 0, 0);
    }
  };

  stage(0, 0);
  asm volatile("s_waitcnt vmcnt(0)" ::: "memory");
  __builtin_amdgcn_s_barrier();
  __builtin_amdgcn_sched_barrier(0);

  int cur = 0;
#pragma unroll
  for (int t = 0; t < 8; t++) {
    if (t < 7) stage((t + 1) * 64, cur ^ 1);
    __builtin_amdgcn_sched_barrier(0);
    compute(cur);
    if (t < 7) {
      asm volatile("s_waitcnt vmcnt(0)" ::: "memory");
      __builtin_amdgcn_s_barrier();
      __builtin_amdgcn_sched_barrier(0);
      cur ^= 1;
    }
  }

  // ---------------- scatter acc -> Q/K/V LDS ----------------
  __syncthreads();   // all waves' P1 reads retired (scatter aliases them)
#pragma unroll
  for (int mt = 0; mt < 8; mt++) {
#pragma unroll
    for (int nt = 0; nt < 3; nt++) {
      const int g = wn * 48 + nt * 16;          // col base; +l16 per lane
      const int proj = g >> 6;                  // uniform over the 16-col tile
      const int j0 = wm * 128 + mt * 16 + quad * 4;
      if (proj == 2) {
        int dcol = (g & 63) + l16;
        unsigned int w0 = (unsigned)f2b(acc[mt][nt][0]) | ((unsigned)f2b(acc[mt][nt][1]) << 16);
        unsigned int w1 = (unsigned)f2b(acc[mt][nt][2]) | ((unsigned)f2b(acc[mt][nt][3]) << 16);
        unsigned int* vp = (unsigned int*)(SM + VT_OFF + dcol * VSTR + j0);
        vp[0] = w0; vp[1] = w1;                 // Vt[dcol][j0..j0+3]
      } else {
        unsigned short* base = SM + (proj ? KL_OFF : QS_OFF);
        int d = (g & 63) + l16;
        int dhi = d >> 3, dlo = d & 7;
#pragma unroll
        for (int r2 = 0; r2 < 4; r2++) {
          int j = j0 + r2;
          base[j * 64 + ((dhi ^ (j & 7)) * 8) + dlo] = f2b(acc[mt][nt][r2]);
        }
      }
    }
  }
  __syncthreads();   // Q/K/V published to all waves

  // ---------------- P2: attention ----------------
  const int u = wave >> 1, par = wave & 1;     // pair u, parity split
  const int tiles2[2] = {u, 7 - u};

  bf16x8 qf[2][2][2];  // [ti][kc][mt]
#pragma unroll
  for (int ti = 0; ti < 2; ti++)
#pragma unroll
    for (int kc = 0; kc < 2; kc++)
#pragma unroll
      for (int mt = 0; mt < 2; mt++) {
        int row = tiles2[ti] * 32 + mt * 16 + l16;
        qf[ti][kc][mt] = *(const bf16x8*)(SM + QS_OFF + row * 64 +
                                          (((kc * 4 + quad) ^ (row & 7)) * 8));
      }

  f32x4 O[2][2][4] = {};      // [ti][mt][dt]
  float lsum[2][2][4] = {};   // [ti][mt][r]
  const float scale = 0.044194173824159216f;  // 1/sqrt(512)

#pragma unroll
  for (int ti = 0; ti < 2; ti++) {
    const int t = tiles2[ti];
    for (int c32 = par; c32 <= t; c32 += 2) {  // wave-uniform trip count
      f32x4 S[2][2] = {};
      __builtin_amdgcn_s_setprio(1);
#pragma unroll
      for (int kc = 0; kc < 2; kc++) {
        bf16x8 kbf[2];
#pragma unroll
        for (int st = 0; st < 2; st++) {
          int jrow = c32 * 32 + st * 16 + l16;
          kbf[st] = *(const bf16x8*)(SM + KL_OFF + jrow * 64 +
                                     (((kc * 4 + quad) ^ (jrow & 7)) * 8));
        }
#pragma unroll
        for (int mt = 0; mt < 2; mt++)
#pragma unroll
          for (int st = 0; st < 2; st++)
            S[mt][st] = __builtin_amdgcn_mfma_f32_16x16x32_bf16(qf[ti][kc][mt], kbf[st], S[mt][st], 0, 0, 0);
      }
      __builtin_amdgcn_s_setprio(0);
      const bool diag = (c32 == t);
#pragma unroll
      for (int mt = 0; mt < 2; mt++)
#pragma unroll
        for (int st = 0; st < 2; st++)
#pragma unroll
          for (int r = 0; r < 4; r++) {
            int trow = mt * 16 + quad * 4 + r;
            float p = __expf(S[mt][st][r] * scale);
            if (diag && (st * 16 + l16 > trow)) p = 0.0f;
            lsum[ti][mt][r] += p;
            SM[PL_OFF + wave * 1280 + trow * 40 + st * 16 + l16] = f2b(p);
          }
      bf16x8 pa[2], vbf[4];
#pragma unroll
      for (int mt = 0; mt < 2; mt++)
        pa[mt] = *(const bf16x8*)(SM + PL_OFF + wave * 1280 + (mt * 16 + l16) * 40 + quad * 8);
#pragma unroll
      for (int dt = 0; dt < 4; dt++)
        vbf[dt] = *(const bf16x8*)(SM + VT_OFF + (dt * 16 + l16) * VSTR + c32 * 32 + quad * 8);
      __builtin_amdgcn_s_setprio(1);
#pragma unroll
      for (int mt = 0; mt < 2; mt++)
#pragma unroll
        for (int dt = 0; dt < 4; dt++)
          O[ti][mt][dt] = __builtin_amdgcn_mfma_f32_16x16x32_bf16(pa[mt], vbf[dt], O[ti][mt][dt], 0, 0, 0);
      __builtin_amdgcn_s_setprio(0);
    }
  }

  // ---------------- P3: pair combine + normalize + write ----------------
  float lred[2][2][4];
#pragma unroll
  for (int ti = 0; ti < 2; ti++)
#pragma unroll
    for (int mt = 0; mt < 2; mt++)
#pragma unroll
      for (int r = 0; r < 4; r++) {
        float s = lsum[ti][mt][r];
        s += __shfl_xor(s, 1); s += __shfl_xor(s, 2);
        s += __shfl_xor(s, 4); s += __shfl_xor(s, 8);
        lred[ti][mt][r] = s;
      }

  __syncthreads();   // all waves done reading Qs/Kl (scratch aliases them)

  float* Oscr = (float*)SM;                       // 4 pairs x 4096 f32 (64 KB)
  float* Lscr = (float*)(SM + PL_OFF);            // 4 pairs x 64 f32

  if (par == 1) {
#pragma unroll
    for (int ti = 0; ti < 2; ti++)
#pragma unroll
      for (int mt = 0; mt < 2; mt++)
#pragma unroll
        for (int dt = 0; dt < 4; dt++)
#pragma unroll
          for (int r = 0; r < 4; r++)
            Oscr[u * 4096 + (ti * 32 + mt * 16 + quad * 4 + r) * 64 + dt * 16 + l16] = O[ti][mt][dt][r];
    if (l16 == 0)
#pragma unroll
      for (int ti = 0; ti < 2; ti++)
#pragma unroll
        for (int mt = 0; mt < 2; mt++)
#pragma unroll
          for (int r = 0; r < 4; r++)
            Lscr[u * 64 + ti * 32 + mt * 16 + quad * 4 + r] = lred[ti][mt][r];
  }
  __syncthreads();

  if (par == 0) {
    float linv[2][2][4];
#pragma unroll
    for (int ti = 0; ti < 2; ti++)
#pragma unroll
      for (int mt = 0; mt < 2; mt++)
#pragma unroll
        for (int r = 0; r < 4; r++)
          linv[ti][mt][r] = 1.0f / (lred[ti][mt][r] +
                                    Lscr[u * 64 + ti * 32 + mt * 16 + quad * 4 + r]);
#pragma unroll
    for (int ti = 0; ti < 2; ti++)
#pragma unroll
      for (int mt = 0; mt < 2; mt++)
#pragma unroll
        for (int dt = 0; dt < 4; dt++)
#pragma unroll
          for (int r = 0; r < 4; r++) {
            float o = O[ti][mt][dt][r] +
                      Oscr[u * 4096 + (ti * 32 + mt * 16 + quad * 4 + r) * 64 + dt * 16 + l16];
            int t_ = tiles2[ti] * 32 + mt * 16 + quad * 4 + r;
            int d = dt * 16 + l16;
            AO[(long)(b * 256 + t_) * 512 + h * 64 + d] = f2b(o * linv[ti][mt][r]);
          }
  }
}

// ---------------------------------------------------------------------------
// C[M x N] = A[M x 512] * BT[N x 512]^T  — round-6 verified 2-phase kernel.
// Used only for the output projection (AO @ WoT -> out, N=512).
// ---------------------------------------------------------------------------
template <int F32OUT>
__global__ __launch_bounds__(256, 2) void gemm_bt(const unsigned short* __restrict__ A,
                                                  const unsigned short* __restrict__ BT,
                                                  void* __restrict__ Cv,
                                                  int N) {
  const int K = 512;
  __shared__ unsigned short As[2][128 * 64];
  __shared__ unsigned short Bs[2][128 * 64];

  const int tid = threadIdx.x;
  const int wave = tid >> 6, lane = tid & 63;
  const int quad = lane >> 4, l16 = lane & 15;
  const int wm = wave >> 1, wn = wave & 1;

  const int NB = N >> 7;
  const int nwg = gridDim.x;
  const int q = nwg >> 3, r = nwg & 7;
  const int xcd = blockIdx.x & 7, ci = blockIdx.x >> 3;
  const int wg = (xcd < r ? xcd * (q + 1) : r * (q + 1) + (xcd - r) * q) + ci;
  const int bn = wg % NB;
  const int bm = wg / NB;

  const int srow = lane >> 3;
  const int scol = ((lane & 7) ^ srow) * 8;

  f32x4 acc[4][4] = {};

  auto stage = [&](int kk, int buf) {
#pragma unroll
    for (int s = 0; s < 4; s++) {
      int seg = wave * 4 + s;
      int row = seg * 8 + srow;
      gll16(A + (long)(bm * 128 + row) * K + kk + scol, &As[buf][seg * 512]);
      gll16(BT + (long)(bn * 128 + row) * K + kk + scol, &Bs[buf][seg * 512]);
    }
  };

  auto compute = [&](int buf) {
#pragma unroll
    for (int kc = 0; kc < 2; kc++) {
      const int rq = (((kc * 4 + quad) ^ (l16 & 7)) * 8);
      bf16x8 af[4], bfv[4];
#pragma unroll
      for (int mt = 0; mt < 4; mt++)
        af[mt] = *(const bf16x8*)(&As[buf][(wm * 64 + mt * 16 + l16) * 64 + rq]);
#pragma unroll
      for (int nt = 0; nt < 4; nt++)
        bfv[nt] = *(const bf16x8*)(&Bs[buf][(wn * 64 + nt * 16 + l16) * 64 + rq]);
#pragma unroll
      for (int mt = 0; mt < 4; mt++)
#pragma unroll
        for (int nt = 0; nt < 4; nt++)
          acc[mt][nt] = __builtin_amdgcn_mfma_f32_16x16x32_bf16(af[mt], bfv[nt], acc[mt][nt], 0, 0, 0);
    }
  };

  stage(0, 0);
  asm volatile("s_waitcnt vmcnt(0)" ::: "memory");
  __builtin_amdgcn_s_barrier();
  __builtin_amdgcn_sched_barrier(0);

  int cur = 0;
#pragma unroll
  for (int t = 0; t < 8; t++) {
    if (t < 7) stage((t + 1) * 64, cur ^ 1);
    __builtin_amdgcn_sched_barrier(0);
    compute(cur);
    if (t < 7) {
      asm volatile("s_waitcnt vmcnt(0)" ::: "memory");
      __builtin_amdgcn_s_barrier();
      __builtin_amdgcn_sched_barrier(0);
      cur ^= 1;
    }
  }

#pragma unroll
  for (int mt = 0; mt < 4; mt++) {
#pragma unroll
    for (int nt = 0; nt < 4; nt++) {
      int row0 = bm * 128 + wm * 64 + mt * 16 + quad * 4;
      int col = bn * 128 + wn * 64 + nt * 16 + l16;
      if (F32OUT) {
        float* cp = (float*)Cv + (long)row0 * N + col;
#pragma unroll
        for (int r2 = 0; r2 < 4; r2++)
          cp[(long)r2 * N] = acc[mt][nt][r2];
      } else {
        unsigned short* cp = (unsigned short*)Cv + (long)row0 * N + col;
#pragma unroll
        for (int r2 = 0; r2 < 4; r2++)
          cp[(long)r2 * N] = f2b(acc[mt][nt][r2]);
      }
    }
  }
}

// ---------------------------------------------------------------------------
extern "C" void kernel_launch(void* const* d_in, const int* in_sizes, int n_in,
                              void* d_out, int out_size, void* d_ws, size_t ws_size,
                              hipStream_t stream) {
  const float* x  = (const float*)d_in[0];   // [16384][512] fp32
  const float* Wq = (const float*)d_in[1];   // [8][512][64] fp32
  const float* Wk = (const float*)d_in[2];
  const float* Wv = (const float*)d_in[3];
  const float* Wo = (const float*)d_in[4];   // [512][512] fp32

  unsigned short* Wt  = (unsigned short*)d_ws;                 // 1536*512
  unsigned short* WoT = Wt + 1536 * 512;                       // 512*512
  unsigned short* xb  = WoT + 512 * 512;                       // 16384*512
  unsigned short* AO  = xb + (long)16384 * 512;                // 16384*512
  float* out = (float*)d_out;                                  // [16384][512] fp32

  prep<<<8448, 256, 0, stream>>>(x, Wq, Wk, Wv, Wo, xb, Wt, WoT);

  qkv_attn<<<512, 512, 0, stream>>>(xb, Wt, AO);

  gemm_bt<1><<<512, 256, 0, stream>>>(AO, WoT, (void*)out, 512);
}